// Round 8
// baseline (130.281 us; speedup 1.0000x reference)
//
#include <hip/hip_runtime.h>
#include <cstdint>
#include <cstddef>

typedef __attribute__((ext_vector_type(8))) short bf16x8;
typedef __attribute__((ext_vector_type(4))) float f32x4;
typedef __attribute__((ext_vector_type(8))) unsigned short u16x8;
typedef __attribute__((ext_vector_type(4))) unsigned short u16x4;

#define NB 8
#define NT 2048
#define ND 768
#define NC 2304     // 3*ND
#define NM (NB*NT)  // 16384
#define SPAN 128

__device__ __forceinline__ unsigned short f2bf(float f) {
    unsigned int u = __builtin_bit_cast(unsigned int, f);
    u += 0x7fffu + ((u >> 16) & 1u);   // RNE
    return (unsigned short)(u >> 16);
}

#define GLOAD16(G, L) __builtin_amdgcn_global_load_lds( \
    (const __attribute__((address_space(1))) unsigned int*)(G), \
    (__attribute__((address_space(3))) unsigned int*)(L), 16, 0, 0)

// ---------------- x (fp32) -> xb (bf16) ----------------
__global__ void k_conv_x(const float* __restrict__ x, unsigned short* __restrict__ xb) {
    int i = blockIdx.x * 256 + threadIdx.x;
    const float4* p = (const float4*)x + (size_t)i * 2;
    float4 a = p[0], b = p[1];
    u16x8 v;
    v[0] = f2bf(a.x); v[1] = f2bf(a.y); v[2] = f2bf(a.z); v[3] = f2bf(a.w);
    v[4] = f2bf(b.x); v[5] = f2bf(b.y); v[6] = f2bf(b.z); v[7] = f2bf(b.w);
    *((u16x8*)xb + i) = v;
}

// ---------------- W [768][2304] fp32 -> wT [2304][768] bf16 ----------------
__global__ void k_conv_wT(const float* __restrict__ W, unsigned short* __restrict__ wT) {
    __shared__ unsigned short tile[64][72];
    const int k0 = blockIdx.x * 64, n0 = blockIdx.y * 64;
    const int tid = threadIdx.x;
    for (int e = 0; e < 16; ++e) {
        int idx = e * 256 + tid;
        int r = idx >> 6, c = idx & 63;
        tile[r][c] = f2bf(W[(size_t)(k0 + r) * NC + n0 + c]);
    }
    __syncthreads();
    for (int e = 0; e < 16; ++e) {
        int idx = e * 256 + tid;
        int r = idx & 63, c = idx >> 6;
        wT[(size_t)(n0 + c) * ND + k0 + r] = tile[r][c];
    }
}

// ---------------- qkv = xb @ W + b : 256x128 tile, BK=64, counted-vmcnt pipeline ----------
// 8 waves (4M x 2N), per-wave 64x64 out (acc[4][4] f32x4 = 64 VGPR).
// LDS: A dbuf 2x32KB @0, B dbuf 2x16KB @64KB (96KB). Row = 128B, swizzle byte^((row&7)<<4).
// Per K-tile: ph0 {8 ds_read kk0; lgkm(0); BAR; 16 MFMA}  ph1 {8 ds_read kk1; lgkm(0); BAR;
// stage(q+2) [writes CURRENT buf - safe: all reads of it proven executed]; 16 MFMA}
// boundary {vmcnt(6); BAR} - counted, drains only at q==10. NO sched_barrier (m141/R2 lesson).
__global__ __launch_bounds__(512, 2) void k_gemm(const unsigned short* __restrict__ xb,
                       const unsigned short* __restrict__ wT,
                       const float* __restrict__ bq,
                       unsigned short* __restrict__ qb,
                       unsigned short* __restrict__ kb,
                       unsigned short* __restrict__ vT) {
    __shared__ char lds[98304];
    const int tid = threadIdx.x, lane = tid & 63, w = tid >> 6;
    // XCD-chunked grid: xcd owns m-stripe == batch xcd (A stripe 3.1MB L2-resident)
    const int bid = blockIdx.x;
    const int xcd = bid & 7, idx = bid >> 3;         // idx 0..143
    const int mb = xcd * 8 + (idx & 7);              // 0..63
    const int nb = idx >> 3;                         // 0..17
    const int m0 = mb * 256, n0 = nb * 128;
    const int wr = (w >> 1) * 64, wc = (w & 1) * 64;

    auto stageA = [&](int q) {                       // 4 loads/thread, 32KB tile [256][64]
        const unsigned short* sb = xb + (size_t)m0 * ND + q * 64;
        char* base = lds + (q & 1) * 32768;
#pragma unroll
        for (int e = 0; e < 4; ++e) {
            int s = e * 512 + w * 64 + lane;
            int r = s >> 3, sl = s & 7;
            GLOAD16(sb + (size_t)r * ND + 8 * (sl ^ (r & 7)), base + (e * 512 + w * 64) * 16);
        }
    };
    auto stageB = [&](int q) {                       // 2 loads/thread, 16KB tile [128][64]
        const unsigned short* sb = wT + (size_t)n0 * ND + q * 64;
        char* base = lds + 65536 + (q & 1) * 16384;
#pragma unroll
        for (int e = 0; e < 2; ++e) {
            int s = e * 512 + w * 64 + lane;
            int r = s >> 3, sl = s & 7;
            GLOAD16(sb + (size_t)r * ND + 8 * (sl ^ (r & 7)), base + (e * 512 + w * 64) * 16);
        }
    };

    f32x4 acc[4][4];
    const f32x4 zf = {0.f, 0.f, 0.f, 0.f};
#pragma unroll
    for (int i = 0; i < 4; ++i)
#pragma unroll
        for (int j = 0; j < 4; ++j) acc[i][j] = zf;

    const int rA = wr + (lane & 15);
    const int rB = wc + (lane & 15);
    const int g16 = (lane >> 4) * 16;
    const int swA = (rA & 7) << 4, swB = (rB & 7) << 4;   // row&7 invariant under +16

    // prologue: tiles 0 and 1 (12 loads); wait oldest 6 (= tile 0)
    stageA(0); stageB(0); stageA(1); stageB(1);
    asm volatile("s_waitcnt vmcnt(6)" ::: "memory");
    __builtin_amdgcn_s_barrier();

#pragma unroll 1
    for (int q = 0; q < 12; ++q) {
        const char* Ab = lds + (q & 1) * 32768;
        const char* Bb = lds + 65536 + (q & 1) * 16384;
        bf16x8 af[4], bg[4];

        // ---- ph0: kk0 ----
#pragma unroll
        for (int mi = 0; mi < 4; ++mi)
            af[mi] = *(const bf16x8*)(Ab + (size_t)(rA + mi * 16) * 128 + (g16 ^ swA));
#pragma unroll
        for (int ni = 0; ni < 4; ++ni)
            bg[ni] = *(const bf16x8*)(Bb + (size_t)(rB + ni * 16) * 128 + (g16 ^ swB));
        asm volatile("s_waitcnt lgkmcnt(0)" ::: "memory");   // reads EXECUTED before BAR
        __builtin_amdgcn_s_barrier();
        __builtin_amdgcn_s_setprio(1);
#pragma unroll
        for (int mi = 0; mi < 4; ++mi)
#pragma unroll
            for (int ni = 0; ni < 4; ++ni)
                acc[mi][ni] = __builtin_amdgcn_mfma_f32_16x16x32_bf16(af[mi], bg[ni], acc[mi][ni], 0, 0, 0);
        __builtin_amdgcn_s_setprio(0);

        // ---- ph1: kk1 ----
#pragma unroll
        for (int mi = 0; mi < 4; ++mi)
            af[mi] = *(const bf16x8*)(Ab + (size_t)(rA + mi * 16) * 128 + ((64 + g16) ^ swA));
#pragma unroll
        for (int ni = 0; ni < 4; ++ni)
            bg[ni] = *(const bf16x8*)(Bb + (size_t)(rB + ni * 16) * 128 + ((64 + g16) ^ swB));
        asm volatile("s_waitcnt lgkmcnt(0)" ::: "memory");
        __builtin_amdgcn_s_barrier();                // all waves' reads of buf q&1 done
        if (q + 2 < 12) { stageA(q + 2); stageB(q + 2); }   // overwrite buf q&1 safely
        __builtin_amdgcn_s_setprio(1);
#pragma unroll
        for (int mi = 0; mi < 4; ++mi)
#pragma unroll
            for (int ni = 0; ni < 4; ++ni)
                acc[mi][ni] = __builtin_amdgcn_mfma_f32_16x16x32_bf16(af[mi], bg[ni], acc[mi][ni], 0, 0, 0);
        __builtin_amdgcn_s_setprio(0);

        // ---- boundary: counted vmcnt (stage(q+2) stays in flight) ----
        if (q < 10) {
            asm volatile("s_waitcnt vmcnt(6)" ::: "memory");
            __builtin_amdgcn_s_barrier();
        } else if (q == 10) {
            asm volatile("s_waitcnt vmcnt(0)" ::: "memory");
            __builtin_amdgcn_s_barrier();
        }
    }

    // ---- epilogue ----
    const int third = nb / 6;
    const int nl0 = (nb % 6) * 128 + wc;
    if (third < 2) {
        unsigned short* ob = third == 0 ? qb : kb;
        float bias[4];
#pragma unroll
        for (int ni = 0; ni < 4; ++ni) bias[ni] = bq[third * ND + nl0 + ni * 16 + (lane & 15)];
#pragma unroll
        for (int mi = 0; mi < 4; ++mi)
#pragma unroll
            for (int e = 0; e < 4; ++e) {
                int m = m0 + wr + mi * 16 + (lane >> 4) * 4 + e;
#pragma unroll
                for (int ni = 0; ni < 4; ++ni)
                    ob[(size_t)m * ND + nl0 + ni * 16 + (lane & 15)] = f2bf(acc[mi][ni][e] + bias[ni]);
            }
    } else {
        // V third: transpose via LDS T[128 d][264 t] -> vT[b][d][t]
        const int bb = m0 >> 11, t0g = m0 & 2047;
        const int d0 = (nb % 6) * 128;
        unsigned short* vTb = vT + ((size_t)bb * ND + d0) * NT;
        float bias[4];
#pragma unroll
        for (int ni = 0; ni < 4; ++ni) bias[ni] = bq[2 * ND + d0 + wc + ni * 16 + (lane & 15)];
        unsigned short* T = (unsigned short*)lds;    // 128*264*2 = 67.6KB (buffers dead)
#pragma unroll
        for (int mi = 0; mi < 4; ++mi)
#pragma unroll
            for (int ni = 0; ni < 4; ++ni) {
                int d_loc = wc + ni * 16 + (lane & 15);
                int t_loc = wr + mi * 16 + (lane >> 4) * 4;
                u16x4 pk;
#pragma unroll
                for (int e = 0; e < 4; ++e) pk[e] = f2bf(acc[mi][ni][e] + bias[ni]);
                *(u16x4*)(T + d_loc * 264 + t_loc) = pk;
            }
        __syncthreads();
#pragma unroll
        for (int e = 0; e < 8; ++e) {                // 128 d x 256 t out, 16B/thread coalesced
            int slot = e * 512 + tid;
            int dd = slot >> 5, ch = slot & 31;
            u16x8 v = *(const u16x8*)(T + dd * 264 + ch * 8);
            *(u16x8*)(vTb + (size_t)dd * NT + t0g + ch * 8) = v;
        }
    }
}

// ---------------- banded attention + fused LN, 16 waves, counted-vmcnt pipelined staging ----
__global__ __launch_bounds__(1024) void k_attn(const unsigned short* __restrict__ qb,
                       const unsigned short* __restrict__ kb,
                       const unsigned short* __restrict__ vT,
                       const float* __restrict__ lnw,
                       const float* __restrict__ lnb,
                       float* __restrict__ out) {
    __shared__ char smem[123904];
    unsigned short* S = (unsigned short*)smem;       // [64][200]
    char* R = smem + 25600;

    const int tid = threadIdx.x, lane = tid & 63, w = tid >> 6;
    const int bid = blockIdx.x;
    const int nid = (bid & 7) * 32 + (bid >> 3);     // batch per XCD (K/V L2-resident)
    const int b = nid >> 5;
    const int q0 = (nid & 31) * 64;
    const size_t rowQ = (size_t)b * NT + q0;
    const size_t rowK = (size_t)b * NT;
    const size_t vbase = (size_t)b * ND * NT;

    f32x4 sacc[3];
    const f32x4 zf = {0.f, 0.f, 0.f, 0.f};
#pragma unroll
    for (int s = 0; s < 3; ++s) sacc[s] = zf;

    const int qrow = (w >> 2) * 16 + (lane & 15);
    const int kct = (w & 3) * 3;

    auto stage_qk = [&](int dc, int cur) {           // 2 gload_lds / thread
        char* L = R + cur * 32768;
#pragma unroll
        for (int e = 0; e < 2; ++e) {
            int s = w * 128 + e * 64 + lane;
            const unsigned short* src;
            if (s < 512) {
                int r = s >> 3, sl = s & 7;
                src = qb + (rowQ + r) * ND + dc * 64 + 8 * (sl ^ (r & 7));
            } else {
                int t = s - 512;
                int r = t >> 3, sl = t & 7;
                int j = q0 - 128 + r; if (j < 0) j = 0;
                src = kb + (rowK + j) * ND + dc * 64 + 8 * (sl ^ (r & 7));
            }
            GLOAD16(src, L + (w * 128 + e * 64) * 16);
        }
    };

    // ---- phase 1: S = Q.K^T, 12 d-chunks; loads stay in flight across barriers ----
    stage_qk(0, 0);
    for (int dc = 0; dc < 12; ++dc) {
        int cur = dc & 1;
        if (dc < 11) {
            stage_qk(dc + 1, cur ^ 1);
            asm volatile("s_waitcnt vmcnt(2)" ::: "memory");   // wait chunk dc only
        } else {
            asm volatile("s_waitcnt vmcnt(0)" ::: "memory");
        }
        __builtin_amdgcn_s_barrier();
        const char* Lq = R + cur * 32768;
        const char* Lk = Lq + 8192;
#pragma unroll
        for (int kk = 0; kk < 2; ++kk) {
            int bq_ = (((lane >> 4) * 16 + kk * 64)) ^ ((qrow & 7) << 4);
            bf16x8 aq = *(const bf16x8*)(Lq + qrow * 128 + bq_);
#pragma unroll
            for (int s = 0; s < 3; ++s) {
                int krow = (kct + s) * 16 + (lane & 15);
                int bk_ = (((lane >> 4) * 16 + kk * 64)) ^ ((krow & 7) << 4);
                bf16x8 bk = *(const bf16x8*)(Lk + krow * 128 + bk_);
                sacc[s] = __builtin_amdgcn_mfma_f32_16x16x32_bf16(aq, bk, sacc[s], 0, 0, 0);
            }
        }
        __builtin_amdgcn_s_barrier();
    }

    // ---- phase 1.5: mask + scale -> S bf16 ----
    const float scl = 0.0031894436f;                 // 1/sqrt(768*128)
#pragma unroll
    for (int s = 0; s < 3; ++s) {
        int jl = (kct + s) * 16 + (lane & 15);
        int j = q0 - 128 + jl;
#pragma unroll
        for (int e = 0; e < 4; ++e) {
            int il = (w >> 2) * 16 + (lane >> 4) * 4 + e;
            int d = (q0 + il) - j;
            float v = (d >= 0 && d < SPAN && j >= 0) ? sacc[s][e] * scl : 0.0f;
            S[il * 200 + jl] = f2bf(v);
        }
    }
    asm volatile("s_waitcnt lgkmcnt(0)" ::: "memory");   // publish S before first V-loop barrier

    auto stage_v = [&](int c, int cur) {             // 3 gload_lds / thread
        char* L = R + cur * 49152;
        int j0 = q0 - 128 + c * 32;
#pragma unroll
        for (int e = 0; e < 3; ++e) {
            int s = w * 192 + e * 64 + lane;
            int d = s >> 2, sl = s & 3;
            int j = j0 + 8 * (sl ^ (d & 3)); if (j < 0) j = 0;
            GLOAD16(vT + vbase + (size_t)d * NT + j, L + (w * 192 + e * 64) * 16);
        }
    };

    f32x4 acc[4][3];
#pragma unroll
    for (int rt = 0; rt < 4; ++rt)
#pragma unroll
        for (int ct = 0; ct < 3; ++ct) acc[rt][ct] = zf;

    // ---- phase 2: out = S @ V, 6 j-chunks; pipelined staging ----
    stage_v(0, 0);
    for (int c = 0; c < 6; ++c) {
        int cur = c & 1;
        if (c < 5) {
            stage_v(c + 1, cur ^ 1);
            asm volatile("s_waitcnt vmcnt(3)" ::: "memory");
        } else {
            asm volatile("s_waitcnt vmcnt(0)" ::: "memory");
        }
        __builtin_amdgcn_s_barrier();
        const char* Lv = R + cur * 49152;
        bf16x8 as[4], bv[3];
#pragma unroll
        for (int rt = 0; rt < 4; ++rt)
            as[rt] = *(const bf16x8*)((const char*)S + (rt * 16 + (lane & 15)) * 400 + c * 64 + (lane >> 4) * 16);
#pragma unroll
        for (int ct = 0; ct < 3; ++ct) {
            int d = (w * 3 + ct) * 16 + (lane & 15);
            bv[ct] = *(const bf16x8*)(Lv + d * 64 + (((lane >> 4) * 16) ^ ((d & 3) << 4)));
        }
#pragma unroll
        for (int rt = 0; rt < 4; ++rt)
#pragma unroll
            for (int ct = 0; ct < 3; ++ct)
                acc[rt][ct] = __builtin_amdgcn_mfma_f32_16x16x32_bf16(as[rt], bv[ct], acc[rt][ct], 0, 0, 0);
        __builtin_amdgcn_s_barrier();
    }

    // ---- fused LN ----
    float psum[4][4], pssq[4][4];
#pragma unroll
    for (int rt = 0; rt < 4; ++rt)
#pragma unroll
        for (int e = 0; e < 4; ++e) {
            float s = 0.f, q = 0.f;
#pragma unroll
            for (int ct = 0; ct < 3; ++ct) { float v = acc[rt][ct][e]; s += v; q += v * v; }
            psum[rt][e] = s; pssq[rt][e] = q;
        }
#pragma unroll
    for (int mx = 1; mx < 16; mx <<= 1)
#pragma unroll
        for (int rt = 0; rt < 4; ++rt)
#pragma unroll
            for (int e = 0; e < 4; ++e) {
                psum[rt][e] += __shfl_xor(psum[rt][e], mx, 64);
                pssq[rt][e] += __shfl_xor(pssq[rt][e], mx, 64);
            }

    float* P = (float*)R;
    float* F = (float*)(R + 8192);
    if ((lane & 15) == 0) {
#pragma unroll
        for (int rt = 0; rt < 4; ++rt)
#pragma unroll
            for (int e = 0; e < 4; ++e) {
                int r = rt * 16 + (lane >> 4) * 4 + e;
                P[(r * 16 + w) * 2] = psum[rt][e];
                P[(r * 16 + w) * 2 + 1] = pssq[rt][e];
            }
    }
    __syncthreads();
    if (tid < 64) {
        float s = 0.f, q = 0.f;
#pragma unroll
        for (int ww = 0; ww < 16; ++ww) { s += P[(tid * 16 + ww) * 2]; q += P[(tid * 16 + ww) * 2 + 1]; }
        float mu = s * (1.0f / 768.0f);
        float var = q * (1.0f / 768.0f) - mu * mu;
        F[tid * 2] = mu;
        F[tid * 2 + 1] = rsqrtf(var + 1e-5f);
    }
    __syncthreads();

    float lw[3], lb_[3];
#pragma unroll
    for (int ct = 0; ct < 3; ++ct) {
        int dcol = (w * 3 + ct) * 16 + (lane & 15);
        lw[ct] = lnw[dcol]; lb_[ct] = lnb[dcol];
    }
#pragma unroll
    for (int rt = 0; rt < 4; ++rt)
#pragma unroll
        for (int e = 0; e < 4; ++e) {
            int row = rt * 16 + (lane >> 4) * 4 + e;
            float mu = F[row * 2], rs = F[row * 2 + 1];
            float* rowp = out + (rowQ + row) * ND;
#pragma unroll
            for (int ct = 0; ct < 3; ++ct) {
                int dcol = (w * 3 + ct) * 16 + (lane & 15);
                rowp[dcol] = (acc[rt][ct][e] - mu) * rs * lw[ct] + lb_[ct];
            }
        }
}

extern "C" void kernel_launch(void* const* d_in, const int* in_sizes, int n_in,
                              void* d_out, int out_size, void* d_ws, size_t ws_size,
                              hipStream_t stream) {
    const float* x   = (const float*)d_in[0];
    const float* W   = (const float*)d_in[1];
    const float* bqv = (const float*)d_in[2];
    const float* lnw = (const float*)d_in[3];
    const float* lnb = (const float*)d_in[4];
    float* out = (float*)d_out;

    char* ws = (char*)d_ws;
    const size_t SZ_XB = (size_t)NM * ND * 2;
    const size_t SZ_WT = (size_t)NC * ND * 2;
    const size_t SZ_P  = (size_t)NM * ND * 2;
    unsigned short* xb = (unsigned short*)ws;
    unsigned short* wT = (unsigned short*)(ws + SZ_XB);
    unsigned short* qb = (unsigned short*)(ws + SZ_XB + SZ_WT);
    unsigned short* kb = (unsigned short*)(ws + SZ_XB + SZ_WT + SZ_P);
    unsigned short* vT = (unsigned short*)(ws + SZ_XB + SZ_WT + 2 * SZ_P);  // written transposed by gemm

    k_conv_x<<<dim3(NM * ND / (256 * 8)), dim3(256), 0, stream>>>(x, xb);
    k_conv_wT<<<dim3(ND / 64, NC / 64), dim3(256), 0, stream>>>(W, wT);
    k_gemm<<<dim3(1152), dim3(512), 0, stream>>>(xb, wT, bqv, qb, kb, vT);
    k_attn<<<dim3(256), dim3(1024), 0, stream>>>(qb, kb, vT, lnw, lnb, out);
}

// Round 9
// 113.989 us; speedup vs baseline: 1.1429x; 1.1429x over previous
//
#include <hip/hip_runtime.h>
#include <cstdint>
#include <cstddef>

typedef __attribute__((ext_vector_type(8))) short bf16x8;
typedef __attribute__((ext_vector_type(4))) float f32x4;
typedef __attribute__((ext_vector_type(8))) unsigned short u16x8;
typedef __attribute__((ext_vector_type(4))) unsigned short u16x4;

#define NB 8
#define NT 2048
#define ND 768
#define NC 2304     // 3*ND
#define NM (NB*NT)  // 16384
#define SPAN 128

__device__ __forceinline__ unsigned short f2bf(float f) {
    unsigned int u = __builtin_bit_cast(unsigned int, f);
    u += 0x7fffu + ((u >> 16) & 1u);   // RNE
    return (unsigned short)(u >> 16);
}

#define GLOAD16(G, L) __builtin_amdgcn_global_load_lds( \
    (const __attribute__((address_space(1))) unsigned int*)(G), \
    (__attribute__((address_space(3))) unsigned int*)(L), 16, 0, 0)

// ---------------- prep: x->bf16 (blocks 0..6143) | W->wT bf16 transpose (blocks 6144..6575) ----
__global__ void k_prep(const float* __restrict__ x, unsigned short* __restrict__ xb,
                       const float* __restrict__ W, unsigned short* __restrict__ wT) {
    __shared__ unsigned short tile[64][72];
    const int bid = blockIdx.x, tid = threadIdx.x;
    if (bid < 6144) {
        int i = bid * 256 + tid;                     // 8 elems per thread, exact grid
        const float4* p = (const float4*)x + (size_t)i * 2;
        float4 a = p[0], b = p[1];
        u16x8 v;
        v[0] = f2bf(a.x); v[1] = f2bf(a.y); v[2] = f2bf(a.z); v[3] = f2bf(a.w);
        v[4] = f2bf(b.x); v[5] = f2bf(b.y); v[6] = f2bf(b.z); v[7] = f2bf(b.w);
        *((u16x8*)xb + i) = v;
    } else {
        int b2 = bid - 6144;
        const int k0 = (b2 % 12) * 64, n0 = (b2 / 12) * 64;
        for (int e = 0; e < 16; ++e) {
            int idx = e * 256 + tid;
            int r = idx >> 6, c = idx & 63;          // r = k, c = n
            tile[r][c] = f2bf(W[(size_t)(k0 + r) * NC + n0 + c]);
        }
        __syncthreads();
        for (int e = 0; e < 16; ++e) {
            int idx = e * 256 + tid;
            int r = idx & 63, c = idx >> 6;          // r = k (fast, coalesced out)
            wT[(size_t)(n0 + c) * ND + k0 + r] = tile[r][c];
        }
    }
}

// ---------------- qkv = xb @ W + b : 128x128 tile, BK=64 (proven structure) ----------
// 4 waves (2x2), acc[4][4] f32x4. A+B staged via swizzled-source global_load_lds.
// q/k epilogue: LDS round-trip -> coalesced u16x8 stores (kills 1.3x write amplification).
// V-third written TRANSPOSED via LDS -> vT[b][d][t].
__global__ void k_gemm(const unsigned short* __restrict__ xb,
                       const unsigned short* __restrict__ wT,
                       const float* __restrict__ bq,
                       unsigned short* __restrict__ qb,
                       unsigned short* __restrict__ kb,
                       unsigned short* __restrict__ vT) {
    __shared__ char lds[32768];
    unsigned short* Asw = (unsigned short*)lds;            // [128 rows][64 k], swizzled
    unsigned short* Bsw = (unsigned short*)(lds + 16384);
    const int tid = threadIdx.x;
    const int lane = tid & 63, w = tid >> 6;
    const int m0 = blockIdx.x * 128, n0 = blockIdx.y * 128;
    const int wr = (w >> 1) * 64, wc = (w & 1) * 64;

    f32x4 acc[4][4];
    const f32x4 zf = {0.f, 0.f, 0.f, 0.f};
#pragma unroll
    for (int i = 0; i < 4; ++i)
#pragma unroll
        for (int j = 0; j < 4; ++j) acc[i][j] = zf;

    for (int kc = 0; kc < 12; ++kc) {
        if (kc) __syncthreads();
#pragma unroll
        for (int t = 0; t < 4; ++t) {
            int chunk = w * 4 + t;                   // 16 x 1024B chunks
            int p = chunk * 1024 + lane * 16;
            int row = p >> 7;
            int col = (p & 127) ^ ((row & 7) << 4);  // byte col within 128B row
            GLOAD16(xb + (size_t)(m0 + row) * ND + kc * 64 + (col >> 1), Asw + chunk * 512);
            GLOAD16(wT + (size_t)(n0 + row) * ND + kc * 64 + (col >> 1), Bsw + chunk * 512);
        }
        __syncthreads();
#pragma unroll
        for (int kk = 0; kk < 2; ++kk) {
            bf16x8 af[4], bg[4];
#pragma unroll
            for (int i = 0; i < 4; ++i) {
                int r = wr + i * 16 + (lane & 15);
                af[i] = *(const bf16x8*)((const char*)Asw + r * 128 +
                        ((kk * 64 + (lane >> 4) * 16) ^ ((r & 7) << 4)));
                int c = wc + i * 16 + (lane & 15);
                bg[i] = *(const bf16x8*)((const char*)Bsw + c * 128 +
                        ((kk * 64 + (lane >> 4) * 16) ^ ((c & 7) << 4)));
            }
#pragma unroll
            for (int i = 0; i < 4; ++i)
#pragma unroll
                for (int j = 0; j < 4; ++j)
                    acc[i][j] = __builtin_amdgcn_mfma_f32_16x16x32_bf16(af[i], bg[j], acc[i][j], 0, 0, 0);
        }
    }

    const int third = n0 / ND;
    if (third < 2) {
        // ---- q/k epilogue: +bias -> LDS [128][128] u16 (XOR-swizzled) -> coalesced stores ----
        unsigned short* ob = third == 0 ? qb : kb;
        const int nl0b = n0 - third * ND;            // block's col-panel base within q/k
        float bias[4];
#pragma unroll
        for (int j = 0; j < 4; ++j) bias[j] = bq[third * ND + nl0b + wc + j * 16 + (lane & 15)];
        __syncthreads();                             // K-loop staging reads complete
        unsigned short* T = (unsigned short*)lds;    // [128 m][256B], slot ^= (row&7)<<4
#pragma unroll
        for (int i = 0; i < 4; ++i)
#pragma unroll
            for (int j = 0; j < 4; ++j) {
                int cb = (wc + j * 16 + (lane & 15)) * 2;            // logical byte col
                int cw = cb & 15, ch = cb & ~15;
#pragma unroll
                for (int r = 0; r < 4; ++r) {
                    int row = wr + i * 16 + (lane >> 4) * 4 + r;
                    *(unsigned short*)((char*)T + row * 256 + (ch ^ ((row & 7) << 4)) + cw)
                        = f2bf(acc[i][j][r] + bias[j]);
                }
            }
        __syncthreads();
#pragma unroll
        for (int e = 0; e < 8; ++e) {                // 2048 slots of 16B, coalesced out
            int slot = e * 256 + tid;
            int row = slot >> 4, ch = slot & 15;
            u16x8 v = *(const u16x8*)((const char*)T + row * 256 + ((ch * 16) ^ ((row & 7) << 4)));
            *(u16x8*)(ob + (size_t)(m0 + row) * ND + nl0b + ch * 8) = v;
        }
    } else {
        // ---- V epilogue: +bias, bf16, TRANSPOSED via LDS -> vT[b][d][t] ----
        const int bb = m0 >> 11, t0g = m0 & 2047;
        const int d0 = n0 - 2 * ND;                  // 0..640, step 128
        unsigned short* vTb = vT + ((size_t)bb * ND + d0) * NT;
        float bias[4];
#pragma unroll
        for (int j = 0; j < 4; ++j) bias[j] = bq[2 * ND + d0 + wc + j * 16 + (lane & 15)];
        unsigned short* T = (unsigned short*)lds;    // [64 d][136 t] u16 = 17.4KB
        for (int h = 0; h < 2; ++h) {                // d-half; uniform barriers
            __syncthreads();
            if ((w & 1) == h) {
#pragma unroll
                for (int i = 0; i < 4; ++i)
#pragma unroll
                    for (int j = 0; j < 4; ++j) {
                        int d_loc = j * 16 + (lane & 15);
                        int t_loc = wr + i * 16 + (lane >> 4) * 4;
                        u16x4 pk;
#pragma unroll
                        for (int r = 0; r < 4; ++r) pk[r] = f2bf(acc[i][j][r] + bias[j]);
                        *(u16x4*)(T + d_loc * 136 + t_loc) = pk;
                    }
            }
            __syncthreads();
#pragma unroll
            for (int e = 0; e < 4; ++e) {            // 64 d-rows x 128 t out, coalesced
                int slot = e * 256 + tid;
                int dd = slot >> 4, ch = slot & 15;
                u16x8 v = *(const u16x8*)(T + dd * 136 + ch * 8);
                *(u16x8*)(vTb + (size_t)(h * 64 + dd) * NT + t0g + ch * 8) = v;
            }
        }
    }
}

// ---------------- banded attention + fused LN, 16 waves, counted-vmcnt pipelined staging ----
__global__ __launch_bounds__(1024) void k_attn(const unsigned short* __restrict__ qb,
                       const unsigned short* __restrict__ kb,
                       const unsigned short* __restrict__ vT,
                       const float* __restrict__ lnw,
                       const float* __restrict__ lnb,
                       float* __restrict__ out) {
    __shared__ char smem[123904];
    unsigned short* S = (unsigned short*)smem;       // [64][200]
    char* R = smem + 25600;

    const int tid = threadIdx.x, lane = tid & 63, w = tid >> 6;
    const int bid = blockIdx.x;
    const int nid = (bid & 7) * 32 + (bid >> 3);     // batch per XCD (K/V L2-resident)
    const int b = nid >> 5;
    const int q0 = (nid & 31) * 64;
    const size_t rowQ = (size_t)b * NT + q0;
    const size_t rowK = (size_t)b * NT;
    const size_t vbase = (size_t)b * ND * NT;

    f32x4 sacc[3];
    const f32x4 zf = {0.f, 0.f, 0.f, 0.f};
#pragma unroll
    for (int s = 0; s < 3; ++s) sacc[s] = zf;

    const int qrow = (w >> 2) * 16 + (lane & 15);
    const int kct = (w & 3) * 3;

    auto stage_qk = [&](int dc, int cur) {           // 2 gload_lds / thread
        char* L = R + cur * 32768;
#pragma unroll
        for (int e = 0; e < 2; ++e) {
            int s = w * 128 + e * 64 + lane;
            const unsigned short* src;
            if (s < 512) {
                int r = s >> 3, sl = s & 7;
                src = qb + (rowQ + r) * ND + dc * 64 + 8 * (sl ^ (r & 7));
            } else {
                int t = s - 512;
                int r = t >> 3, sl = t & 7;
                int j = q0 - 128 + r; if (j < 0) j = 0;
                src = kb + (rowK + j) * ND + dc * 64 + 8 * (sl ^ (r & 7));
            }
            GLOAD16(src, L + (w * 128 + e * 64) * 16);
        }
    };

    // ---- phase 1: S = Q.K^T, 12 d-chunks; loads stay in flight across barriers ----
    stage_qk(0, 0);
    for (int dc = 0; dc < 12; ++dc) {
        int cur = dc & 1;
        if (dc < 11) {
            stage_qk(dc + 1, cur ^ 1);
            asm volatile("s_waitcnt vmcnt(2)" ::: "memory");   // wait chunk dc only
        } else {
            asm volatile("s_waitcnt vmcnt(0)" ::: "memory");
        }
        __builtin_amdgcn_s_barrier();
        const char* Lq = R + cur * 32768;
        const char* Lk = Lq + 8192;
#pragma unroll
        for (int kk = 0; kk < 2; ++kk) {
            int bq_ = (((lane >> 4) * 16 + kk * 64)) ^ ((qrow & 7) << 4);
            bf16x8 aq = *(const bf16x8*)(Lq + qrow * 128 + bq_);
#pragma unroll
            for (int s = 0; s < 3; ++s) {
                int krow = (kct + s) * 16 + (lane & 15);
                int bk_ = (((lane >> 4) * 16 + kk * 64)) ^ ((krow & 7) << 4);
                bf16x8 bk = *(const bf16x8*)(Lk + krow * 128 + bk_);
                sacc[s] = __builtin_amdgcn_mfma_f32_16x16x32_bf16(aq, bk, sacc[s], 0, 0, 0);
            }
        }
        __builtin_amdgcn_s_barrier();
    }

    // ---- phase 1.5: mask + scale -> S bf16 ----
    const float scl = 0.0031894436f;                 // 1/sqrt(768*128)
#pragma unroll
    for (int s = 0; s < 3; ++s) {
        int jl = (kct + s) * 16 + (lane & 15);
        int j = q0 - 128 + jl;
#pragma unroll
        for (int e = 0; e < 4; ++e) {
            int il = (w >> 2) * 16 + (lane >> 4) * 4 + e;
            int d = (q0 + il) - j;
            float v = (d >= 0 && d < SPAN && j >= 0) ? sacc[s][e] * scl : 0.0f;
            S[il * 200 + jl] = f2bf(v);
        }
    }
    asm volatile("s_waitcnt lgkmcnt(0)" ::: "memory");   // publish S before first V-loop barrier

    auto stage_v = [&](int c, int cur) {             // 3 gload_lds / thread
        char* L = R + cur * 49152;
        int j0 = q0 - 128 + c * 32;
#pragma unroll
        for (int e = 0; e < 3; ++e) {
            int s = w * 192 + e * 64 + lane;
            int d = s >> 2, sl = s & 3;
            int j = j0 + 8 * (sl ^ (d & 3)); if (j < 0) j = 0;
            GLOAD16(vT + vbase + (size_t)d * NT + j, L + (w * 192 + e * 64) * 16);
        }
    };

    f32x4 acc[4][3];
#pragma unroll
    for (int rt = 0; rt < 4; ++rt)
#pragma unroll
        for (int ct = 0; ct < 3; ++ct) acc[rt][ct] = zf;

    // ---- phase 2: out = S @ V, 6 j-chunks; pipelined staging ----
    stage_v(0, 0);
    for (int c = 0; c < 6; ++c) {
        int cur = c & 1;
        if (c < 5) {
            stage_v(c + 1, cur ^ 1);
            asm volatile("s_waitcnt vmcnt(3)" ::: "memory");
        } else {
            asm volatile("s_waitcnt vmcnt(0)" ::: "memory");
        }
        __builtin_amdgcn_s_barrier();
        const char* Lv = R + cur * 49152;
        bf16x8 as[4], bv[3];
#pragma unroll
        for (int rt = 0; rt < 4; ++rt)
            as[rt] = *(const bf16x8*)((const char*)S + (rt * 16 + (lane & 15)) * 400 + c * 64 + (lane >> 4) * 16);
#pragma unroll
        for (int ct = 0; ct < 3; ++ct) {
            int d = (w * 3 + ct) * 16 + (lane & 15);
            bv[ct] = *(const bf16x8*)(Lv + d * 64 + (((lane >> 4) * 16) ^ ((d & 3) << 4)));
        }
#pragma unroll
        for (int rt = 0; rt < 4; ++rt)
#pragma unroll
            for (int ct = 0; ct < 3; ++ct)
                acc[rt][ct] = __builtin_amdgcn_mfma_f32_16x16x32_bf16(as[rt], bv[ct], acc[rt][ct], 0, 0, 0);
        __builtin_amdgcn_s_barrier();
    }

    // ---- fused LN ----
    float psum[4][4], pssq[4][4];
#pragma unroll
    for (int rt = 0; rt < 4; ++rt)
#pragma unroll
        for (int e = 0; e < 4; ++e) {
            float s = 0.f, q = 0.f;
#pragma unroll
            for (int ct = 0; ct < 3; ++ct) { float v = acc[rt][ct][e]; s += v; q += v * v; }
            psum[rt][e] = s; pssq[rt][e] = q;
        }
#pragma unroll
    for (int mx = 1; mx < 16; mx <<= 1)
#pragma unroll
        for (int rt = 0; rt < 4; ++rt)
#pragma unroll
            for (int e = 0; e < 4; ++e) {
                psum[rt][e] += __shfl_xor(psum[rt][e], mx, 64);
                pssq[rt][e] += __shfl_xor(pssq[rt][e], mx, 64);
            }

    float* P = (float*)R;
    float* F = (float*)(R + 8192);
    if ((lane & 15) == 0) {
#pragma unroll
        for (int rt = 0; rt < 4; ++rt)
#pragma unroll
            for (int e = 0; e < 4; ++e) {
                int r = rt * 16 + (lane >> 4) * 4 + e;
                P[(r * 16 + w) * 2] = psum[rt][e];
                P[(r * 16 + w) * 2 + 1] = pssq[rt][e];
            }
    }
    __syncthreads();
    if (tid < 64) {
        float s = 0.f, q = 0.f;
#pragma unroll
        for (int ww = 0; ww < 16; ++ww) { s += P[(tid * 16 + ww) * 2]; q += P[(tid * 16 + ww) * 2 + 1]; }
        float mu = s * (1.0f / 768.0f);
        float var = q * (1.0f / 768.0f) - mu * mu;
        F[tid * 2] = mu;
        F[tid * 2 + 1] = rsqrtf(var + 1e-5f);
    }
    __syncthreads();

    float lw[3], lb_[3];
#pragma unroll
    for (int ct = 0; ct < 3; ++ct) {
        int dcol = (w * 3 + ct) * 16 + (lane & 15);
        lw[ct] = lnw[dcol]; lb_[ct] = lnb[dcol];
    }
#pragma unroll
    for (int rt = 0; rt < 4; ++rt)
#pragma unroll
        for (int e = 0; e < 4; ++e) {
            int row = rt * 16 + (lane >> 4) * 4 + e;
            float mu = F[row * 2], rs = F[row * 2 + 1];
            float* rowp = out + (rowQ + row) * ND;
#pragma unroll
            for (int ct = 0; ct < 3; ++ct) {
                int dcol = (w * 3 + ct) * 16 + (lane & 15);
                rowp[dcol] = (acc[rt][ct][e] - mu) * rs * lw[ct] + lb_[ct];
            }
        }
}

extern "C" void kernel_launch(void* const* d_in, const int* in_sizes, int n_in,
                              void* d_out, int out_size, void* d_ws, size_t ws_size,
                              hipStream_t stream) {
    const float* x   = (const float*)d_in[0];
    const float* W   = (const float*)d_in[1];
    const float* bqv = (const float*)d_in[2];
    const float* lnw = (const float*)d_in[3];
    const float* lnb = (const float*)d_in[4];
    float* out = (float*)d_out;

    char* ws = (char*)d_ws;
    const size_t SZ_XB = (size_t)NM * ND * 2;
    const size_t SZ_WT = (size_t)NC * ND * 2;
    const size_t SZ_P  = (size_t)NM * ND * 2;
    unsigned short* xb = (unsigned short*)ws;
    unsigned short* wT = (unsigned short*)(ws + SZ_XB);
    unsigned short* qb = (unsigned short*)(ws + SZ_XB + SZ_WT);
    unsigned short* kb = (unsigned short*)(ws + SZ_XB + SZ_WT + SZ_P);
    unsigned short* vT = (unsigned short*)(ws + SZ_XB + SZ_WT + 2 * SZ_P);  // written transposed by gemm

    k_prep<<<dim3(6576), dim3(256), 0, stream>>>(x, xb, W, wT);
    k_gemm<<<dim3(NM / 128, NC / 128), dim3(256), 0, stream>>>(xb, wT, bqv, qb, kb, vT);
    k_attn<<<dim3(256), dim3(1024), 0, stream>>>(qb, kb, vT, lnw, lnb, out);
}